// Round 1
// baseline (344.483 us; speedup 1.0000x reference)
//
#include <hip/hip_runtime.h>
#include <hip/hip_bf16.h>
#include <cstdint>
#include <cstddef>

typedef __hip_bfloat16 bf16;
typedef __attribute__((ext_vector_type(4))) float f32x4;
typedef __attribute__((ext_vector_type(8))) short s16x8;

// ---- async global->LDS, 16B per lane. Dest is wave-uniform base + lane*16. ----
__device__ __forceinline__ void gload_lds16(const void* g, void* l) {
    __builtin_amdgcn_global_load_lds(
        (const __attribute__((address_space(1))) unsigned int*)g,
        (__attribute__((address_space(3))) unsigned int*)l,
        16, 0, 0);
}

__device__ __forceinline__ short f2bs(float x) {
    bf16 h = __float2bfloat16(x);
    return *reinterpret_cast<short*>(&h);
}

// =======================================================================
// Generic GEMM body: C[m,n] = act( sum_k A[m,k]*B[n,k] + bias[n] ) * Mul[m,n]
//   Tile: BM=BN=128, BK=64. 256 threads = 4 waves, each wave 64x64 out.
//   LDS slot (row, c) holds global chunk (row, c ^ (row&7))  (8-bf16 chunks).
//   ASRC/BSRC: 0 = bf16 source via global_load_lds (async, linear dest)
//              1 = f32 source, reg-staged float4->bf16 convert->ds_write_b128
//              2 = f32 source gathered by gidx rows (A only)
//   Conversion uses the same __float2bfloat16 as the old standalone cvt
//   kernels -> bitwise-identical operands, absmax unchanged.
// =======================================================================
template<int TANH, int MULW, int F32OUT, int NGUARD, int ASRC, int BSRC>
__device__ __forceinline__ void gemm_body(
    short* __restrict__ sA, short* __restrict__ sB,
    int bm, int bn,
    const void* __restrict__ Aptr, const void* __restrict__ Bptr,
    const int* __restrict__ gidx,
    const float* __restrict__ bias, const float* __restrict__ Mul,
    void* __restrict__ Cout, int M, int N, int K, int ldc)
{
    const int tid  = threadIdx.x;
    const int lane = tid & 63;
    const int wave = tid >> 6;
    const int wr = wave >> 1, wc = wave & 1;
    const int l15 = lane & 15, quad = lane >> 4;

    // ---- per-j staging descriptors (kt-invariant; gather idx hoisted) ----
    int    slot[4];
    size_t a_off[4], b_off[4];
#pragma unroll
    for (int j = 0; j < 4; ++j) {
        int S   = (wave * 4 + j) * 64 + lane;   // LDS chunk slot
        int row = S >> 3;
        int cc  = (S & 7) ^ (row & 7);          // swizzled source chunk
        slot[j] = S * 8;
        if (ASRC == 2)
            a_off[j] = (size_t)gidx[bm * 128 + row] * K + cc * 8;
        else
            a_off[j] = (size_t)(bm * 128 + row) * K + cc * 8;
        int ng = bn * 128 + row;
        if (NGUARD) ng = (ng < N) ? ng : (N - 1);
        b_off[j] = (size_t)ng * K + cc * 8;
    }

    f32x4 acc[4][4];
#pragma unroll
    for (int i = 0; i < 4; ++i)
#pragma unroll
        for (int j = 0; j < 4; ++j)
            acc[i][j] = (f32x4){0.f, 0.f, 0.f, 0.f};

    for (int kt = 0; kt < K; kt += 64) {
        // ---- stage A ----
#pragma unroll
        for (int j = 0; j < 4; ++j) {
            if (ASRC == 0) {
                gload_lds16((const bf16*)Aptr + a_off[j] + kt, &sA[slot[j]]);
            } else {
                const float* s = (const float*)Aptr + a_off[j] + kt;
                float4 u = *(const float4*)s;
                float4 v = *(const float4*)(s + 4);
                s16x8 p;
                p[0] = f2bs(u.x); p[1] = f2bs(u.y); p[2] = f2bs(u.z); p[3] = f2bs(u.w);
                p[4] = f2bs(v.x); p[5] = f2bs(v.y); p[6] = f2bs(v.z); p[7] = f2bs(v.w);
                *(s16x8*)&sA[slot[j]] = p;
            }
        }
        // ---- stage B ----
#pragma unroll
        for (int j = 0; j < 4; ++j) {
            if (BSRC == 0) {
                gload_lds16((const bf16*)Bptr + b_off[j] + kt, &sB[slot[j]]);
            } else {
                const float* s = (const float*)Bptr + b_off[j] + kt;
                float4 u = *(const float4*)s;
                float4 v = *(const float4*)(s + 4);
                s16x8 p;
                p[0] = f2bs(u.x); p[1] = f2bs(u.y); p[2] = f2bs(u.z); p[3] = f2bs(u.w);
                p[4] = f2bs(v.x); p[5] = f2bs(v.y); p[6] = f2bs(v.z); p[7] = f2bs(v.w);
                *(s16x8*)&sB[slot[j]] = p;
            }
        }
        if (ASRC == 0 || BSRC == 0)
            asm volatile("s_waitcnt vmcnt(0)" ::: "memory");
        __syncthreads();

#pragma unroll
        for (int ks = 0; ks < 2; ++ks) {
            s16x8 afr[4], bfr[4];
#pragma unroll
            for (int i = 0; i < 4; ++i) {
                int r = wr * 64 + i * 16 + l15;
                int q = ks * 4 + quad;
                afr[i] = *(const s16x8*)&sA[(r * 8 + (q ^ (r & 7))) * 8];
            }
#pragma unroll
            for (int j = 0; j < 4; ++j) {
                int r = wc * 64 + j * 16 + l15;
                int q = ks * 4 + quad;
                bfr[j] = *(const s16x8*)&sB[(r * 8 + (q ^ (r & 7))) * 8];
            }
#pragma unroll
            for (int i = 0; i < 4; ++i)
#pragma unroll
                for (int j = 0; j < 4; ++j)
                    acc[i][j] = __builtin_amdgcn_mfma_f32_16x16x32_bf16(
                        afr[i], bfr[j], acc[i][j], 0, 0, 0);
        }
        __syncthreads();
    }

    // ---- epilogue. C/D layout: col = lane&15, row = quad*4 + reg ----
#pragma unroll
    for (int j = 0; j < 4; ++j) {
        int colg = bn * 128 + wc * 64 + j * 16 + l15;
        if (NGUARD && colg >= N) continue;
        float bv = bias[colg];
#pragma unroll
        for (int i = 0; i < 4; ++i) {
            int row0 = bm * 128 + wr * 64 + i * 16 + quad * 4;
#pragma unroll
            for (int r = 0; r < 4; ++r) {
                float v = acc[i][j][r] + bv;
                if (TANH) v = tanhf(v);
                if (MULW) v *= Mul[(size_t)(row0 + r) * N + colg];
                if (F32OUT)
                    ((float*)Cout)[(size_t)(row0 + r) * ldc + colg] = v;
                else
                    ((bf16*)Cout)[(size_t)(row0 + r) * ldc + colg] = __float2bfloat16(v);
            }
        }
    }
}

// =======================================================================
// Merged launch 1: [0,192)  -> z = gather(AGE_inx,Endx) @ W_age^T + b_age (f32)
//                  [192,320)-> h = tanh(t @ W_prjT^T + b_prjT)            (bf16)
// Both depend only on raw inputs -> run concurrently in one grid.
// =======================================================================
__global__ __launch_bounds__(256)
void mm_zh(const float* __restrict__ AGEinx, const int* __restrict__ Endx,
           const float* __restrict__ W_age, const float* __restrict__ b_age,
           float* __restrict__ z,
           const float* __restrict__ t, const float* __restrict__ W_prjT,
           const float* __restrict__ b_prjT, bf16* __restrict__ h)
{
    __shared__ short sA[128 * 64];
    __shared__ short sB[128 * 64];
    int b = blockIdx.x;
    if (b < 192) {
        // old grid dim3(6,32): bn = x, bm = y
        gemm_body<0, 0, 1, 0, 2, 1>(sA, sB, b / 6, b % 6,
                                    AGEinx, W_age, Endx, b_age, nullptr,
                                    z, 4096, 768, 768, 768);
    } else {
        int b2 = b - 192;   // old grid dim3(2,64)
        gemm_body<1, 0, 0, 0, 1, 1>(sA, sB, b2 / 2, b2 % 2,
                                    t, W_prjT, nullptr, b_prjT, nullptr,
                                    h, 8192, 256, 768, 256);
    }
}

// =======================================================================
// E2 = tanh(AGE_E @ W_prjL^T + b_prjL) * outW   (bf16)
// =======================================================================
__global__ __launch_bounds__(256)
void mm_e2(const bf16* __restrict__ AGE_E, const float* __restrict__ W_prjL,
           const float* __restrict__ b_prjL, const float* __restrict__ outW,
           bf16* __restrict__ E2)
{
    __shared__ short sA[128 * 64];
    __shared__ short sB[128 * 64];
    gemm_body<1, 1, 0, 0, 0, 1>(sA, sB, blockIdx.y, blockIdx.x,
                                AGE_E, W_prjL, nullptr, b_prjL, outW,
                                E2, 4096, 256, 768, 256);
}

// =======================================================================
// Merged launch 4: [0,2048)   -> o_c = h @ E2^T + outb      (f32)
//                  [2048,2112)-> o_f = h @ W_fc3^T + b_fc3  (f32, N=50 guarded)
// =======================================================================
__global__ __launch_bounds__(256)
void mm_out(const bf16* __restrict__ h, const bf16* __restrict__ E2,
            const float* __restrict__ outb, float* __restrict__ o_c,
            const float* __restrict__ W_fc3, const float* __restrict__ b_fc3,
            float* __restrict__ o_f)
{
    __shared__ short sA[128 * 64];
    __shared__ short sB[128 * 64];
    int b = blockIdx.x;
    if (b < 2048) {
        // old grid dim3(32,64)
        gemm_body<0, 0, 1, 0, 0, 0>(sA, sB, b / 32, b % 32,
                                    h, E2, nullptr, outb, nullptr,
                                    o_c, 8192, 4096, 256, 4096);
    } else {
        int b2 = b - 2048;  // old grid dim3(1,64)
        gemm_body<0, 0, 1, 1, 0, 1>(sA, sB, b2, 0,
                                    h, W_fc3, nullptr, b_fc3, nullptr,
                                    o_f, 8192, 50, 256, 50);
    }
}

// =======================================================================
// lintrans rows: z[row,:768] (fp32) -> minmax scale -> L2 norm -> bf16
// =======================================================================
__global__ __launch_bounds__(256)
void lintrans_k(const float* __restrict__ z, bf16* __restrict__ out)
{
    __shared__ float rmin[4], rmax[4], rsum[4];
    const int row  = blockIdx.x;
    const int tid  = threadIdx.x;
    const int lane = tid & 63;
    const int wave = tid >> 6;
    const float* zr = z + (size_t)row * 768;

    float v0 = zr[tid], v1 = zr[tid + 256], v2 = zr[tid + 512];
    float mn = fminf(fminf(v0, v1), v2);
    float mx = fmaxf(fmaxf(v0, v1), v2);
#pragma unroll
    for (int o = 32; o > 0; o >>= 1) {
        mn = fminf(mn, __shfl_down(mn, o));
        mx = fmaxf(mx, __shfl_down(mx, o));
    }
    if (lane == 0) { rmin[wave] = mn; rmax[wave] = mx; }
    __syncthreads();
    float bmn = fminf(fminf(rmin[0], rmin[1]), fminf(rmin[2], rmin[3]));
    float bmx = fmaxf(fmaxf(rmax[0], rmax[1]), fmaxf(rmax[2], rmax[3]));
    float sc  = 1.f / (bmx - bmn);
    v0 = (v0 - bmn) * sc; v1 = (v1 - bmn) * sc; v2 = (v2 - bmn) * sc;
    float s = v0 * v0 + v1 * v1 + v2 * v2;
#pragma unroll
    for (int o = 32; o > 0; o >>= 1) s += __shfl_down(s, o);
    if (lane == 0) rsum[wave] = s;
    __syncthreads();
    float tot = rsum[0] + rsum[1] + rsum[2] + rsum[3];
    float inv = 1.f / fmaxf(sqrtf(tot), 1e-12f);
    out[(size_t)row * 768 + tid]       = __float2bfloat16(v0 * inv);
    out[(size_t)row * 768 + tid + 256] = __float2bfloat16(v1 * inv);
    out[(size_t)row * 768 + tid + 512] = __float2bfloat16(v2 * inv);
}

// =======================================================================
extern "C" void kernel_launch(void* const* d_in, const int* in_sizes, int n_in,
                              void* d_out, int out_size, void* d_ws, size_t ws_size,
                              hipStream_t stream)
{
    (void)in_sizes; (void)n_in; (void)out_size; (void)ws_size;

    const float* t_in   = (const float*)d_in[0];   // [8192,768]
    const float* AGEinx = (const float*)d_in[1];   // [20000,768]
    const int*   Endx   = (const int*)  d_in[2];   // [4096]
    const float* W_age  = (const float*)d_in[3];   // [768,768]
    const float* b_age  = (const float*)d_in[4];   // [768]
    const float* W_prjT = (const float*)d_in[5];   // [256,768]
    const float* b_prjT = (const float*)d_in[6];   // [256]
    const float* W_prjL = (const float*)d_in[7];   // [256,768]
    const float* b_prjL = (const float*)d_in[8];   // [256]
    const float* outW   = (const float*)d_in[9];   // [4096,256]
    const float* outb   = (const float*)d_in[10];  // [4096]
    const float* W_fc3  = (const float*)d_in[11];  // [50,256]
    const float* b_fc3  = (const float*)d_in[12];  // [50]

    char* ws = (char*)d_ws;
    size_t off = 0;
    // NOTE: z and h are now live CONCURRENTLY (mm_zh computes both) -> no alias.
    float* z     = (float*)(ws + off); off += (size_t)4096 * 768 * 4;  // 12.58 MB
    bf16*  h     = (bf16*) (ws + off); off += (size_t)8192 * 256 * 2;  //  4.19 MB
    bf16*  AGE_E = (bf16*) (ws + off); off += (size_t)4096 * 768 * 2;  //  6.29 MB
    bf16*  E2    = (bf16*) (ws + off); off += (size_t)4096 * 256 * 2;  //  2.10 MB

    float* o_c = (float*)d_out;                    // [8192,4096]
    float* o_f = o_c + (size_t)8192 * 4096;        // [8192,50]

    // L1: z (gather+cvt fused) || h (cvt fused). 320 blocks, one launch.
    mm_zh<<<320, 256, 0, stream>>>(AGEinx, Endx, W_age, b_age, z,
                                   t_in, W_prjT, b_prjT, h);
    // L2: AGE_E = lintrans(z)
    lintrans_k<<<4096, 256, 0, stream>>>(z, AGE_E);
    // L3: E2 = tanh(AGE_E @ W_prjL^T + b_prjL) * outW  (W_prjL cvt fused)
    mm_e2<<<dim3(2, 32), 256, 0, stream>>>(AGE_E, W_prjL, b_prjL, outW, E2);
    // L4: o_c || o_f. 2112 blocks, one launch.
    mm_out<<<2112, 256, 0, stream>>>(h, E2, outb, o_c, W_fc3, b_fc3, o_f);
}

// Round 3
// 312.471 us; speedup vs baseline: 1.1024x; 1.1024x over previous
//
#include <hip/hip_runtime.h>
#include <hip/hip_bf16.h>
#include <cstdint>
#include <cstddef>

typedef __hip_bfloat16 bf16;
typedef __attribute__((ext_vector_type(4))) float f32x4;
typedef __attribute__((ext_vector_type(8))) short s16x8;

// ---- async global->LDS, 16B per lane. Dest is wave-uniform base + lane*16. ----
__device__ __forceinline__ void gload_lds16(const void* g, void* l) {
    __builtin_amdgcn_global_load_lds(
        (const __attribute__((address_space(1))) unsigned int*)g,
        (__attribute__((address_space(3))) unsigned int*)l,
        16, 0, 0);
}

__device__ __forceinline__ short f2bs(float x) {
    bf16 h = __float2bfloat16(x);
    return *reinterpret_cast<short*>(&h);
}

__device__ __forceinline__ s16x8 pack8(f32x4 u, f32x4 v) {
    s16x8 p;
    p[0] = f2bs(u[0]); p[1] = f2bs(u[1]); p[2] = f2bs(u[2]); p[3] = f2bs(u[3]);
    p[4] = f2bs(v[0]); p[5] = f2bs(v[1]); p[6] = f2bs(v[2]); p[7] = f2bs(v[3]);
    return p;
}

// =======================================================================
// Generic GEMM body: C[m,n] = act( sum_k A[m,k]*B[n,k] + bias[n] ) * Mul[m,n]
//   Tile: BM=BN=128, BK=64. 256 threads = 4 waves, each wave 64x64 out.
//   LDS slot (row, c) holds global chunk (row, c ^ (row&7))  (8-bf16 chunks).
//   ASRC/BSRC: 0 = bf16 source via global_load_lds (async, linear dest)
//              1 = f32 source, reg-staged float4->bf16 convert->ds_write_b128
//              2 = f32 source gathered by gidx rows (A only)
//   T14 async-STAGE: f32 operands for tile kt+1 are loaded into registers
//   BETWEEN the barrier and the MFMA phase of tile kt, so HBM latency hides
//   under MFMA. The end-of-loop __syncthreads() fence keeps the loads from
//   sinking past the MFMA region; the compiler waits only at next-iter use.
// =======================================================================
template<int TANH, int MULW, int F32OUT, int NGUARD, int ASRC, int BSRC>
__device__ __forceinline__ void gemm_body(
    short* __restrict__ sA, short* __restrict__ sB,
    int bm, int bn,
    const void* __restrict__ Aptr, const void* __restrict__ Bptr,
    const int* __restrict__ gidx,
    const float* __restrict__ bias, const float* __restrict__ Mul,
    void* __restrict__ Cout, int M, int N, int K, int ldc)
{
    const int tid  = threadIdx.x;
    const int lane = tid & 63;
    const int wave = tid >> 6;
    const int wr = wave >> 1, wc = wave & 1;
    const int l15 = lane & 15, quad = lane >> 4;

    // ---- per-j staging descriptors (kt-invariant; gather idx hoisted) ----
    int    slot[4];
    size_t a_off[4], b_off[4];
#pragma unroll
    for (int j = 0; j < 4; ++j) {
        int S   = (wave * 4 + j) * 64 + lane;   // LDS chunk slot
        int row = S >> 3;
        int cc  = (S & 7) ^ (row & 7);          // swizzled source chunk
        slot[j] = S * 8;
        if (ASRC == 2)
            a_off[j] = (size_t)gidx[bm * 128 + row] * K + cc * 8;
        else
            a_off[j] = (size_t)(bm * 128 + row) * K + cc * 8;
        int ng = bn * 128 + row;
        if (NGUARD) ng = (ng < N) ? ng : (N - 1);
        b_off[j] = (size_t)ng * K + cc * 8;
    }

    f32x4 acc[4][4];
#pragma unroll
    for (int i = 0; i < 4; ++i)
#pragma unroll
        for (int j = 0; j < 4; ++j)
            acc[i][j] = (f32x4){0.f, 0.f, 0.f, 0.f};

    // ---- prologue: prefetch tile kt=0 f32 operands into registers ----
    f32x4 pa0[4], pa1[4], pb0[4], pb1[4];
    if (ASRC != 0) {
#pragma unroll
        for (int j = 0; j < 4; ++j) {
            const float* s = (const float*)Aptr + a_off[j];
            pa0[j] = *(const f32x4*)s;
            pa1[j] = *(const f32x4*)(s + 4);
        }
    }
    if (BSRC != 0) {
#pragma unroll
        for (int j = 0; j < 4; ++j) {
            const float* s = (const float*)Bptr + b_off[j];
            pb0[j] = *(const f32x4*)s;
            pb1[j] = *(const f32x4*)(s + 4);
        }
    }

    for (int kt = 0; kt < K; kt += 64) {
        // ---- stage A (from prefetch regs, or async gload_lds) ----
#pragma unroll
        for (int j = 0; j < 4; ++j) {
            if (ASRC == 0)
                gload_lds16((const bf16*)Aptr + a_off[j] + kt, &sA[slot[j]]);
            else
                *(s16x8*)&sA[slot[j]] = pack8(pa0[j], pa1[j]);
        }
        // ---- stage B ----
#pragma unroll
        for (int j = 0; j < 4; ++j) {
            if (BSRC == 0)
                gload_lds16((const bf16*)Bptr + b_off[j] + kt, &sB[slot[j]]);
            else
                *(s16x8*)&sB[slot[j]] = pack8(pb0[j], pb1[j]);
        }
        if (ASRC == 0 || BSRC == 0)
            asm volatile("s_waitcnt vmcnt(0)" ::: "memory");
        __syncthreads();

        // ---- T14: issue next tile's f32 loads now; latency hides under MFMA ----
        if (kt + 64 < K) {
            if (ASRC != 0) {
#pragma unroll
                for (int j = 0; j < 4; ++j) {
                    const float* s = (const float*)Aptr + a_off[j] + kt + 64;
                    pa0[j] = *(const f32x4*)s;
                    pa1[j] = *(const f32x4*)(s + 4);
                }
            }
            if (BSRC != 0) {
#pragma unroll
                for (int j = 0; j < 4; ++j) {
                    const float* s = (const float*)Bptr + b_off[j] + kt + 64;
                    pb0[j] = *(const f32x4*)s;
                    pb1[j] = *(const f32x4*)(s + 4);
                }
            }
        }

#pragma unroll
        for (int ks = 0; ks < 2; ++ks) {
            s16x8 afr[4], bfr[4];
#pragma unroll
            for (int i = 0; i < 4; ++i) {
                int r = wr * 64 + i * 16 + l15;
                int q = ks * 4 + quad;
                afr[i] = *(const s16x8*)&sA[(r * 8 + (q ^ (r & 7))) * 8];
            }
#pragma unroll
            for (int j = 0; j < 4; ++j) {
                int r = wc * 64 + j * 16 + l15;
                int q = ks * 4 + quad;
                bfr[j] = *(const s16x8*)&sB[(r * 8 + (q ^ (r & 7))) * 8];
            }
#pragma unroll
            for (int i = 0; i < 4; ++i)
#pragma unroll
                for (int j = 0; j < 4; ++j)
                    acc[i][j] = __builtin_amdgcn_mfma_f32_16x16x32_bf16(
                        afr[i], bfr[j], acc[i][j], 0, 0, 0);
        }
        __syncthreads();
    }

    // ---- epilogue. C/D layout: col = lane&15, row = quad*4 + reg ----
#pragma unroll
    for (int j = 0; j < 4; ++j) {
        int colg = bn * 128 + wc * 64 + j * 16 + l15;
        if (NGUARD && colg >= N) continue;
        float bv = bias[colg];
#pragma unroll
        for (int i = 0; i < 4; ++i) {
            int row0 = bm * 128 + wr * 64 + i * 16 + quad * 4;
#pragma unroll
            for (int r = 0; r < 4; ++r) {
                float v = acc[i][j][r] + bv;
                if (TANH) v = tanhf(v);
                if (MULW) v *= Mul[(size_t)(row0 + r) * N + colg];
                if (F32OUT)
                    ((float*)Cout)[(size_t)(row0 + r) * ldc + colg] = v;
                else
                    ((bf16*)Cout)[(size_t)(row0 + r) * ldc + colg] = __float2bfloat16(v);
            }
        }
    }
}

// =======================================================================
// L1: z = gather(AGE_inx,Endx) @ W_age^T + b_age  (f32 out). 192 blocks,
// whole machine to itself (it heads the serial chain).
// =======================================================================
__global__ __launch_bounds__(256)
void mm_z(const float* __restrict__ AGEinx, const int* __restrict__ Endx,
          const float* __restrict__ W_age, const float* __restrict__ b_age,
          float* __restrict__ z)
{
    __shared__ short sA[128 * 64];
    __shared__ short sB[128 * 64];
    int b = blockIdx.x;
    gemm_body<0, 0, 1, 0, 2, 1>(sA, sB, b / 6, b % 6,
                                AGEinx, W_age, Endx, b_age, nullptr,
                                z, 4096, 768, 768, 768);
}

// =======================================================================
// L3 merged: [0,128)   -> h  = tanh(t @ W_prjT^T + b_prjT)            (bf16)
//            [128,192) -> E2 = tanh(AGE_E @ W_prjL^T + b_prjL) * outW (bf16)
// h depends only on inputs; E2 needs AGE_E. Merging fills 192 blocks where
// E2 alone used 64 (25% of CUs).
// =======================================================================
__global__ __launch_bounds__(256)
void mm_he2(const float* __restrict__ t, const float* __restrict__ W_prjT,
            const float* __restrict__ b_prjT, bf16* __restrict__ h,
            const bf16* __restrict__ AGE_E, const float* __restrict__ W_prjL,
            const float* __restrict__ b_prjL, const float* __restrict__ outW,
            bf16* __restrict__ E2)
{
    __shared__ short sA[128 * 64];
    __shared__ short sB[128 * 64];
    int b = blockIdx.x;
    if (b < 128) {
        gemm_body<1, 0, 0, 0, 1, 1>(sA, sB, b / 2, b % 2,
                                    t, W_prjT, nullptr, b_prjT, nullptr,
                                    h, 8192, 256, 768, 256);
    } else {
        int b2 = b - 128;
        gemm_body<1, 1, 0, 0, 0, 1>(sA, sB, b2 / 2, b2 % 2,
                                    AGE_E, W_prjL, nullptr, b_prjL, outW,
                                    E2, 4096, 256, 768, 256);
    }
}

// =======================================================================
// L4 merged: [0,2048)   -> o_c = h @ E2^T + outb      (f32)
//            [2048,2112)-> o_f = h @ W_fc3^T + b_fc3  (f32, N=50 guarded)
// o_c region gets T1 XCD swizzle (2048%8==0 -> simple form is bijective):
// h+E2 = 6.3 MB > 4 MB per-XCD L2; chunked bm keeps panel re-reads L2-hot.
// =======================================================================
__global__ __launch_bounds__(256)
void mm_out(const bf16* __restrict__ h, const bf16* __restrict__ E2,
            const float* __restrict__ outb, float* __restrict__ o_c,
            const float* __restrict__ W_fc3, const float* __restrict__ b_fc3,
            float* __restrict__ o_f)
{
    __shared__ short sA[128 * 64];
    __shared__ short sB[128 * 64];
    int b = blockIdx.x;
    if (b < 2048) {
        int bs = (b & 7) * 256 + (b >> 3);   // XCD-aware remap, bijective
        gemm_body<0, 0, 1, 0, 0, 0>(sA, sB, bs / 32, bs % 32,
                                    h, E2, nullptr, outb, nullptr,
                                    o_c, 8192, 4096, 256, 4096);
    } else {
        int b2 = b - 2048;
        gemm_body<0, 0, 1, 1, 0, 1>(sA, sB, b2, 0,
                                    h, W_fc3, nullptr, b_fc3, nullptr,
                                    o_f, 8192, 50, 256, 50);
    }
}

// =======================================================================
// lintrans rows: z[row,:768] (fp32) -> minmax scale -> L2 norm -> bf16
// =======================================================================
__global__ __launch_bounds__(256)
void lintrans_k(const float* __restrict__ z, bf16* __restrict__ out)
{
    __shared__ float rmin[4], rmax[4], rsum[4];
    const int row  = blockIdx.x;
    const int tid  = threadIdx.x;
    const int lane = tid & 63;
    const int wave = tid >> 6;
    const float* zr = z + (size_t)row * 768;

    float v0 = zr[tid], v1 = zr[tid + 256], v2 = zr[tid + 512];
    float mn = fminf(fminf(v0, v1), v2);
    float mx = fmaxf(fmaxf(v0, v1), v2);
#pragma unroll
    for (int o = 32; o > 0; o >>= 1) {
        mn = fminf(mn, __shfl_down(mn, o));
        mx = fmaxf(mx, __shfl_down(mx, o));
    }
    if (lane == 0) { rmin[wave] = mn; rmax[wave] = mx; }
    __syncthreads();
    float bmn = fminf(fminf(rmin[0], rmin[1]), fminf(rmin[2], rmin[3]));
    float bmx = fmaxf(fmaxf(rmax[0], rmax[1]), fmaxf(rmax[2], rmax[3]));
    float sc  = 1.f / (bmx - bmn);
    v0 = (v0 - bmn) * sc; v1 = (v1 - bmn) * sc; v2 = (v2 - bmn) * sc;
    float s = v0 * v0 + v1 * v1 + v2 * v2;
#pragma unroll
    for (int o = 32; o > 0; o >>= 1) s += __shfl_down(s, o);
    if (lane == 0) rsum[wave] = s;
    __syncthreads();
    float tot = rsum[0] + rsum[1] + rsum[2] + rsum[3];
    float inv = 1.f / fmaxf(sqrtf(tot), 1e-12f);
    out[(size_t)row * 768 + tid]       = __float2bfloat16(v0 * inv);
    out[(size_t)row * 768 + tid + 256] = __float2bfloat16(v1 * inv);
    out[(size_t)row * 768 + tid + 512] = __float2bfloat16(v2 * inv);
}

// =======================================================================
extern "C" void kernel_launch(void* const* d_in, const int* in_sizes, int n_in,
                              void* d_out, int out_size, void* d_ws, size_t ws_size,
                              hipStream_t stream)
{
    (void)in_sizes; (void)n_in; (void)out_size; (void)ws_size;

    const float* t_in   = (const float*)d_in[0];   // [8192,768]
    const float* AGEinx = (const float*)d_in[1];   // [20000,768]
    const int*   Endx   = (const int*)  d_in[2];   // [4096]
    const float* W_age  = (const float*)d_in[3];   // [768,768]
    const float* b_age  = (const float*)d_in[4];   // [768]
    const float* W_prjT = (const float*)d_in[5];   // [256,768]
    const float* b_prjT = (const float*)d_in[6];   // [256]
    const float* W_prjL = (const float*)d_in[7];   // [256,768]
    const float* b_prjL = (const float*)d_in[8];   // [256]
    const float* outW   = (const float*)d_in[9];   // [4096,256]
    const float* outb   = (const float*)d_in[10];  // [4096]
    const float* W_fc3  = (const float*)d_in[11];  // [50,256]
    const float* b_fc3  = (const float*)d_in[12];  // [50]

    char* ws = (char*)d_ws;
    size_t off = 0;
    // z dies after lintrans (L2); h is born in L3 -> h aliases z.
    float* z     = (float*)(ws + off);
    bf16*  h     = (bf16*) (ws + off); off += (size_t)4096 * 768 * 4;  // 12.58 MB
    bf16*  AGE_E = (bf16*) (ws + off); off += (size_t)4096 * 768 * 2;  //  6.29 MB
    bf16*  E2    = (bf16*) (ws + off); off += (size_t)4096 * 256 * 2;  //  2.10 MB

    float* o_c = (float*)d_out;                    // [8192,4096]
    float* o_f = o_c + (size_t)8192 * 4096;        // [8192,50]

    // L1: z (gather+cvt fused, T14-pipelined)
    mm_z<<<192, 256, 0, stream>>>(AGEinx, Endx, W_age, b_age, z);
    // L2: AGE_E = lintrans(z)
    lintrans_k<<<4096, 256, 0, stream>>>(z, AGE_E);
    // L3: h || E2 (both T14-pipelined). 192 blocks.
    mm_he2<<<192, 256, 0, stream>>>(t_in, W_prjT, b_prjT, h,
                                    AGE_E, W_prjL, b_prjL, outW, E2);
    // L4: o_c (XCD-swizzled) || o_f. 2112 blocks.
    mm_out<<<2112, 256, 0, stream>>>(h, E2, outb, o_c, W_fc3, b_fc3, o_f);
}

// Round 4
// 299.531 us; speedup vs baseline: 1.1501x; 1.0432x over previous
//
#include <hip/hip_runtime.h>
#include <hip/hip_bf16.h>
#include <cstdint>
#include <cstddef>

typedef __hip_bfloat16 bf16;
typedef __attribute__((ext_vector_type(4))) float f32x4;
typedef __attribute__((ext_vector_type(8))) short s16x8;

// ---- async global->LDS, 16B per lane. Dest is wave-uniform base + lane*16. ----
__device__ __forceinline__ void gload_lds16(const void* g, void* l) {
    __builtin_amdgcn_global_load_lds(
        (const __attribute__((address_space(1))) unsigned int*)g,
        (__attribute__((address_space(3))) unsigned int*)l,
        16, 0, 0);
}

__device__ __forceinline__ short f2bs(float x) {
    bf16 h = __float2bfloat16(x);
    return *reinterpret_cast<short*>(&h);
}

__device__ __forceinline__ s16x8 pack8(f32x4 u, f32x4 v) {
    s16x8 p;
    p[0] = f2bs(u[0]); p[1] = f2bs(u[1]); p[2] = f2bs(u[2]); p[3] = f2bs(u[3]);
    p[4] = f2bs(v[0]); p[5] = f2bs(v[1]); p[6] = f2bs(v[2]); p[7] = f2bs(v[3]);
    return p;
}

// =======================================================================
// Generic GEMM body: C[m,n] = act( sum_k A[m,k]*B[n,k] + bias[n] ) * Mul[m,n]
//   Tile: BM=BN=128, BK=64. 256 threads = 4 waves, each wave 64x64 out.
//   sAB: 2*128*64 shorts (32 KB). First half A, second half B in main loop;
//   whole buffer reused as f32 scratch for the vectorized epilogue.
//   ASRC/BSRC: 0 = bf16 source via global_load_lds (async, linear dest)
//              1 = f32 source, reg-staged float4->bf16 convert->ds_write_b128
//              2 = f32 source gathered by gidx rows (A only)
//   T14 async-STAGE: f32 operands for tile kt+1 are loaded into registers
//   between barrier and MFMA so HBM latency hides under MFMA.
//   Epilogue (non-NGUARD): per-wave LDS transpose of the 64x64 output tile
//   (two 32-col halves, XOR-swizzled -> 2-way bank aliasing = free), then
//   dwordx4 / 16B-packed-bf16 stores: 64 scalar stores -> 16 (f32) or
//   8 (bf16) wide stores per thread. Values pass through LDS bit-exactly.
// =======================================================================
template<int TANH, int MULW, int F32OUT, int NGUARD, int ASRC, int BSRC>
__device__ __forceinline__ void gemm_body(
    short* __restrict__ sAB,
    int bm, int bn,
    const void* __restrict__ Aptr, const void* __restrict__ Bptr,
    const int* __restrict__ gidx,
    const float* __restrict__ bias, const float* __restrict__ Mul,
    void* __restrict__ Cout, int M, int N, int K, int ldc)
{
    short* sA = sAB;
    short* sB = sAB + 128 * 64;

    const int tid  = threadIdx.x;
    const int lane = tid & 63;
    const int wave = tid >> 6;
    const int wr = wave >> 1, wc = wave & 1;
    const int l15 = lane & 15, quad = lane >> 4;

    // ---- per-j staging descriptors (kt-invariant; gather idx hoisted) ----
    int    slot[4];
    size_t a_off[4], b_off[4];
#pragma unroll
    for (int j = 0; j < 4; ++j) {
        int S   = (wave * 4 + j) * 64 + lane;   // LDS chunk slot
        int row = S >> 3;
        int cc  = (S & 7) ^ (row & 7);          // swizzled source chunk
        slot[j] = S * 8;
        if (ASRC == 2)
            a_off[j] = (size_t)gidx[bm * 128 + row] * K + cc * 8;
        else
            a_off[j] = (size_t)(bm * 128 + row) * K + cc * 8;
        int ng = bn * 128 + row;
        if (NGUARD) ng = (ng < N) ? ng : (N - 1);
        b_off[j] = (size_t)ng * K + cc * 8;
    }

    f32x4 acc[4][4];
#pragma unroll
    for (int i = 0; i < 4; ++i)
#pragma unroll
        for (int j = 0; j < 4; ++j)
            acc[i][j] = (f32x4){0.f, 0.f, 0.f, 0.f};

    // ---- prologue: prefetch tile kt=0 f32 operands into registers ----
    f32x4 pa0[4], pa1[4], pb0[4], pb1[4];
    if (ASRC != 0) {
#pragma unroll
        for (int j = 0; j < 4; ++j) {
            const float* s = (const float*)Aptr + a_off[j];
            pa0[j] = *(const f32x4*)s;
            pa1[j] = *(const f32x4*)(s + 4);
        }
    }
    if (BSRC != 0) {
#pragma unroll
        for (int j = 0; j < 4; ++j) {
            const float* s = (const float*)Bptr + b_off[j];
            pb0[j] = *(const f32x4*)s;
            pb1[j] = *(const f32x4*)(s + 4);
        }
    }

    for (int kt = 0; kt < K; kt += 64) {
        // ---- stage A (from prefetch regs, or async gload_lds) ----
#pragma unroll
        for (int j = 0; j < 4; ++j) {
            if (ASRC == 0)
                gload_lds16((const bf16*)Aptr + a_off[j] + kt, &sA[slot[j]]);
            else
                *(s16x8*)&sA[slot[j]] = pack8(pa0[j], pa1[j]);
        }
        // ---- stage B ----
#pragma unroll
        for (int j = 0; j < 4; ++j) {
            if (BSRC == 0)
                gload_lds16((const bf16*)Bptr + b_off[j] + kt, &sB[slot[j]]);
            else
                *(s16x8*)&sB[slot[j]] = pack8(pb0[j], pb1[j]);
        }
        if (ASRC == 0 || BSRC == 0)
            asm volatile("s_waitcnt vmcnt(0)" ::: "memory");
        __syncthreads();

        // ---- T14: issue next tile's f32 loads now; latency hides under MFMA ----
        if (kt + 64 < K) {
            if (ASRC != 0) {
#pragma unroll
                for (int j = 0; j < 4; ++j) {
                    const float* s = (const float*)Aptr + a_off[j] + kt + 64;
                    pa0[j] = *(const f32x4*)s;
                    pa1[j] = *(const f32x4*)(s + 4);
                }
            }
            if (BSRC != 0) {
#pragma unroll
                for (int j = 0; j < 4; ++j) {
                    const float* s = (const float*)Bptr + b_off[j] + kt + 64;
                    pb0[j] = *(const f32x4*)s;
                    pb1[j] = *(const f32x4*)(s + 4);
                }
            }
        }

#pragma unroll
        for (int ks = 0; ks < 2; ++ks) {
            s16x8 afr[4], bfr[4];
#pragma unroll
            for (int i = 0; i < 4; ++i) {
                int r = wr * 64 + i * 16 + l15;
                int q = ks * 4 + quad;
                afr[i] = *(const s16x8*)&sA[(r * 8 + (q ^ (r & 7))) * 8];
            }
#pragma unroll
            for (int j = 0; j < 4; ++j) {
                int r = wc * 64 + j * 16 + l15;
                int q = ks * 4 + quad;
                bfr[j] = *(const s16x8*)&sB[(r * 8 + (q ^ (r & 7))) * 8];
            }
#pragma unroll
            for (int i = 0; i < 4; ++i)
#pragma unroll
                for (int j = 0; j < 4; ++j)
                    acc[i][j] = __builtin_amdgcn_mfma_f32_16x16x32_bf16(
                        afr[i], bfr[j], acc[i][j], 0, 0, 0);
        }
        __syncthreads();
    }

    // =========================== epilogue ==============================
    // C/D layout: col = lane&15, row = quad*4 + reg
    if (NGUARD) {
        // scalar path (o_f: N=50, partial 16B chunks at the boundary)
#pragma unroll
        for (int j = 0; j < 4; ++j) {
            int colg = bn * 128 + wc * 64 + j * 16 + l15;
            if (colg >= N) continue;
            float bv = bias[colg];
#pragma unroll
            for (int i = 0; i < 4; ++i) {
                int row0 = bm * 128 + wr * 64 + i * 16 + quad * 4;
#pragma unroll
                for (int r = 0; r < 4; ++r) {
                    float v = acc[i][j][r] + bv;
                    if (TANH) v = tanhf(v);
                    if (MULW) v *= Mul[(size_t)(row0 + r) * N + colg];
                    if (F32OUT)
                        ((float*)Cout)[(size_t)(row0 + r) * ldc + colg] = v;
                    else
                        ((bf16*)Cout)[(size_t)(row0 + r) * ldc + colg] = __float2bfloat16(v);
                }
            }
        }
        return;
    }

    // Vectorized path: per-wave 64x64 tile, two 32-col halves through LDS.
    float* wt = (float*)sAB + wave * 2048;   // 64 rows x 32 cols f32 (8 KB)
#pragma unroll
    for (int half = 0; half < 2; ++half) {
        // -- write phase: activation applied, then swizzled LDS store --
#pragma unroll
        for (int jj = 0; jj < 2; ++jj) {
            int j = half * 2 + jj;
            int colg = bn * 128 + wc * 64 + j * 16 + l15;
            float bv = bias[colg];
#pragma unroll
            for (int i = 0; i < 4; ++i) {
                int row0 = bm * 128 + wr * 64 + i * 16 + quad * 4;
#pragma unroll
                for (int r = 0; r < 4; ++r) {
                    float v = acc[i][j][r] + bv;
                    if (TANH) v = tanhf(v);
                    if (MULW) v *= Mul[(size_t)(row0 + r) * N + colg];
                    int lrow = i * 16 + quad * 4 + r;
                    int lcol = jj * 16 + l15;
                    wt[lrow * 32 + (lcol ^ ((lrow & 7) << 2))] = v;
                }
            }
        }
        __syncthreads();
        // -- read + wide-store phase --
        if (F32OUT) {
            int r8 = lane >> 3, seg = lane & 7;
#pragma unroll
            for (int ii = 0; ii < 8; ++ii) {
                int lrow = ii * 8 + r8;
                f32x4 v = *(const f32x4*)&wt[lrow * 32 + ((seg * 4) ^ ((lrow & 7) << 2))];
                size_t ro = (size_t)(bm * 128 + wr * 64 + lrow) * ldc
                          + bn * 128 + wc * 64 + half * 32 + seg * 4;
                *(f32x4*)&((float*)Cout)[ro] = v;
            }
        } else {
            int r4 = lane >> 2, sg = lane & 3;
#pragma unroll
            for (int ii = 0; ii < 4; ++ii) {
                int lrow = ii * 16 + r4;
                int c0 = sg * 8;
                f32x4 u = *(const f32x4*)&wt[lrow * 32 + ((c0    ) ^ ((lrow & 7) << 2))];
                f32x4 w = *(const f32x4*)&wt[lrow * 32 + ((c0 + 4) ^ ((lrow & 7) << 2))];
                s16x8 p = pack8(u, w);
                size_t ro = (size_t)(bm * 128 + wr * 64 + lrow) * ldc
                          + bn * 128 + wc * 64 + half * 32 + c0;
                *(s16x8*)&((bf16*)Cout)[ro] = p;
            }
        }
        __syncthreads();   // protect wt before next half / kernel end
    }
}

// =======================================================================
// L1: z = gather(AGE_inx,Endx) @ W_age^T + b_age  (f32 out). 192 blocks.
// =======================================================================
__global__ __launch_bounds__(256)
void mm_z(const float* __restrict__ AGEinx, const int* __restrict__ Endx,
          const float* __restrict__ W_age, const float* __restrict__ b_age,
          float* __restrict__ z)
{
    __shared__ short sAB[2 * 128 * 64];
    int b = blockIdx.x;
    gemm_body<0, 0, 1, 0, 2, 1>(sAB, b / 6, b % 6,
                                AGEinx, W_age, Endx, b_age, nullptr,
                                z, 4096, 768, 768, 768);
}

// =======================================================================
// L3 merged: [0,128)   -> h  = tanh(t @ W_prjT^T + b_prjT)            (bf16)
//            [128,192) -> E2 = tanh(AGE_E @ W_prjL^T + b_prjL) * outW (bf16)
// =======================================================================
__global__ __launch_bounds__(256)
void mm_he2(const float* __restrict__ t, const float* __restrict__ W_prjT,
            const float* __restrict__ b_prjT, bf16* __restrict__ h,
            const bf16* __restrict__ AGE_E, const float* __restrict__ W_prjL,
            const float* __restrict__ b_prjL, const float* __restrict__ outW,
            bf16* __restrict__ E2)
{
    __shared__ short sAB[2 * 128 * 64];
    int b = blockIdx.x;
    if (b < 128) {
        gemm_body<1, 0, 0, 0, 1, 1>(sAB, b / 2, b % 2,
                                    t, W_prjT, nullptr, b_prjT, nullptr,
                                    h, 8192, 256, 768, 256);
    } else {
        int b2 = b - 128;
        gemm_body<1, 1, 0, 0, 0, 1>(sAB, b2 / 2, b2 % 2,
                                    AGE_E, W_prjL, nullptr, b_prjL, outW,
                                    E2, 4096, 256, 768, 256);
    }
}

// =======================================================================
// L4 merged: [0,2048)   -> o_c = h @ E2^T + outb      (f32, XCD-swizzled)
//            [2048,2112)-> o_f = h @ W_fc3^T + b_fc3  (f32, N=50 guarded)
// =======================================================================
__global__ __launch_bounds__(256)
void mm_out(const bf16* __restrict__ h, const bf16* __restrict__ E2,
            const float* __restrict__ outb, float* __restrict__ o_c,
            const float* __restrict__ W_fc3, const float* __restrict__ b_fc3,
            float* __restrict__ o_f)
{
    __shared__ short sAB[2 * 128 * 64];
    int b = blockIdx.x;
    if (b < 2048) {
        int bs = (b & 7) * 256 + (b >> 3);   // XCD-aware remap, bijective
        gemm_body<0, 0, 1, 0, 0, 0>(sAB, bs / 32, bs % 32,
                                    h, E2, nullptr, outb, nullptr,
                                    o_c, 8192, 4096, 256, 4096);
    } else {
        int b2 = b - 2048;
        gemm_body<0, 0, 1, 1, 0, 1>(sAB, b2, 0,
                                    h, W_fc3, nullptr, b_fc3, nullptr,
                                    o_f, 8192, 50, 256, 50);
    }
}

// =======================================================================
// lintrans rows: z[row,:768] (fp32) -> minmax scale -> L2 norm -> bf16
// =======================================================================
__global__ __launch_bounds__(256)
void lintrans_k(const float* __restrict__ z, bf16* __restrict__ out)
{
    __shared__ float rmin[4], rmax[4], rsum[4];
    const int row  = blockIdx.x;
    const int tid  = threadIdx.x;
    const int lane = tid & 63;
    const int wave = tid >> 6;
    const float* zr = z + (size_t)row * 768;

    float v0 = zr[tid], v1 = zr[tid + 256], v2 = zr[tid + 512];
    float mn = fminf(fminf(v0, v1), v2);
    float mx = fmaxf(fmaxf(v0, v1), v2);
#pragma unroll
    for (int o = 32; o > 0; o >>= 1) {
        mn = fminf(mn, __shfl_down(mn, o));
        mx = fmaxf(mx, __shfl_down(mx, o));
    }
    if (lane == 0) { rmin[wave] = mn; rmax[wave] = mx; }
    __syncthreads();
    float bmn = fminf(fminf(rmin[0], rmin[1]), fminf(rmin[2], rmin[3]));
    float bmx = fmaxf(fmaxf(rmax[0], rmax[1]), fmaxf(rmax[2], rmax[3]));
    float sc  = 1.f / (bmx - bmn);
    v0 = (v0 - bmn) * sc; v1 = (v1 - bmn) * sc; v2 = (v2 - bmn) * sc;
    float s = v0 * v0 + v1 * v1 + v2 * v2;
#pragma unroll
    for (int o = 32; o > 0; o >>= 1) s += __shfl_down(s, o);
    if (lane == 0) rsum[wave] = s;
    __syncthreads();
    float tot = rsum[0] + rsum[1] + rsum[2] + rsum[3];
    float inv = 1.f / fmaxf(sqrtf(tot), 1e-12f);
    out[(size_t)row * 768 + tid]       = __float2bfloat16(v0 * inv);
    out[(size_t)row * 768 + tid + 256] = __float2bfloat16(v1 * inv);
    out[(size_t)row * 768 + tid + 512] = __float2bfloat16(v2 * inv);
}

// =======================================================================
extern "C" void kernel_launch(void* const* d_in, const int* in_sizes, int n_in,
                              void* d_out, int out_size, void* d_ws, size_t ws_size,
                              hipStream_t stream)
{
    (void)in_sizes; (void)n_in; (void)out_size; (void)ws_size;

    const float* t_in   = (const float*)d_in[0];   // [8192,768]
    const float* AGEinx = (const float*)d_in[1];   // [20000,768]
    const int*   Endx   = (const int*)  d_in[2];   // [4096]
    const float* W_age  = (const float*)d_in[3];   // [768,768]
    const float* b_age  = (const float*)d_in[4];   // [768]
    const float* W_prjT = (const float*)d_in[5];   // [256,768]
    const float* b_prjT = (const float*)d_in[6];   // [256]
    const float* W_prjL = (const float*)d_in[7];   // [256,768]
    const float* b_prjL = (const float*)d_in[8];   // [256]
    const float* outW   = (const float*)d_in[9];   // [4096,256]
    const float* outb   = (const float*)d_in[10];  // [4096]
    const float* W_fc3  = (const float*)d_in[11];  // [50,256]
    const float* b_fc3  = (const float*)d_in[12];  // [50]

    char* ws = (char*)d_ws;
    size_t off = 0;
    // z dies after lintrans (L2); h is born in L3 -> h aliases z.
    float* z     = (float*)(ws + off);
    bf16*  h     = (bf16*) (ws + off); off += (size_t)4096 * 768 * 4;  // 12.58 MB
    bf16*  AGE_E = (bf16*) (ws + off); off += (size_t)4096 * 768 * 2;  //  6.29 MB
    bf16*  E2    = (bf16*) (ws + off); off += (size_t)4096 * 256 * 2;  //  2.10 MB

    float* o_c = (float*)d_out;                    // [8192,4096]
    float* o_f = o_c + (size_t)8192 * 4096;        // [8192,50]

    // L1: z (gather+cvt fused, T14-pipelined)
    mm_z<<<192, 256, 0, stream>>>(AGEinx, Endx, W_age, b_age, z);
    // L2: AGE_E = lintrans(z)
    lintrans_k<<<4096, 256, 0, stream>>>(z, AGE_E);
    // L3: h || E2 (both T14-pipelined). 192 blocks.
    mm_he2<<<192, 256, 0, stream>>>(t_in, W_prjT, b_prjT, h,
                                    AGE_E, W_prjL, b_prjL, outW, E2);
    // L4: o_c (XCD-swizzled, vectorized epilogue) || o_f. 2112 blocks.
    mm_out<<<2112, 256, 0, stream>>>(h, E2, outb, o_c, W_fc3, b_fc3, o_f);
}